// Round 1
// baseline (1730.386 us; speedup 1.0000x reference)
//
#include <hip/hip_runtime.h>

#define N_EDGES 400000
#define EB 128            // edges per block (400000 = 3125 * 128, exact)
#define XQS 52            // x(40) + q(8) row stride, 16B-aligned, bank-spread

static constexpr float INV_SQRT3 = 0.5773502691896257f;
static constexpr float PW0 = 0.20412414523193154f;   // sqrt(1/24)
static constexpr float PW1 = 0.35355339059327373f;   // sqrt(3/24)
static constexpr float SILU_NORM = 1.6791767923989418f;

// Accumulate acc[e][c] += (coef[e]*h[e][k]) * W2[k][cb+c] over k=0..64.
// hp points at h_s[0][4g]; one ds_read_b128 per k serves 4 edges.
// W2 addresses are identical for the 8 lanes of a group -> broadcast loads.
template<int NC>
__device__ __forceinline__ void acc_chunk(const float* __restrict__ W2c,
                                          const float* __restrict__ hp,
                                          const float (&coef)[4],
                                          float (&acc)[4][NC])
{
#pragma unroll 2
    for (int k = 0; k < 64; ++k) {
        float4 h4 = *(const float4*)(hp + k * EB);
        const float4* r4 = (const float4*)(W2c + k * 576);
        float4 b[NC/4];
#pragma unroll
        for (int q = 0; q < NC/4; ++q) b[q] = r4[q];
        const float he[4] = {coef[0]*h4.x, coef[1]*h4.y, coef[2]*h4.z, coef[3]*h4.w};
#pragma unroll
        for (int e = 0; e < 4; ++e)
#pragma unroll
            for (int q = 0; q < NC/4; ++q) {
                acc[e][q*4+0] += he[e] * b[q].x;
                acc[e][q*4+1] += he[e] * b[q].y;
                acc[e][q*4+2] += he[e] * b[q].z;
                acc[e][q*4+3] += he[e] * b[q].w;
            }
    }
}

__global__ __launch_bounds__(256) void conv_fused(
    const float* __restrict__ node_input,
    const int* __restrict__ edge_src,
    const int* __restrict__ edge_dst,
    const float* __restrict__ edge_attr,
    const float* __restrict__ dist_embedding,
    const float* __restrict__ W1,
    const float* __restrict__ W2,
    float* __restrict__ out)
{
    __shared__ float h_s[64 * EB];       // h_s[k][e]  (transposed), 32 KB
    __shared__ float xq_s[EB * XQS];     // per edge: x[0..40), q[40..48)
    __shared__ int   src_s[EB];

    const int t  = threadIdx.x;
    const int e0 = blockIdx.x * EB;

    // ---------------- phase B: edge data -> LDS --------------------------
    if (t < EB) {
        const int e = e0 + t;
        src_s[t] = edge_src[e];
        const int dst = edge_dst[e];
        const float4* xr = (const float4*)(node_input + (size_t)dst * 40);
        float4* xd = (float4*)(xq_s + t * XQS);
#pragma unroll
        for (int i = 0; i < 10; ++i) xd[i] = xr[i];
    } else {
        const int el2 = t - EB;
        const float4 yv = *(const float4*)(edge_attr + (size_t)(e0 + el2) * 4);
        const float SC  = 0.03125f;                 // 1/sqrt(64) * 1/sqrt(16)
        const float kP1 = PW1 * INV_SQRT3 * SC;
        const float q4  = PW0 * INV_SQRT3 * SC;
        float* qd = xq_s + el2 * XQS + 40;
        qd[0] = PW0 * SC * yv.x;   // q0  = PW0*y0*SC
        qd[1] = kP1 * yv.x;        // q3  = kP1*y0
        qd[2] = kP1 * yv.y;        // q20
        qd[3] = kP1 * yv.z;        // q21
        qd[4] = kP1 * yv.w;        // q22
        qd[5] = q4 * yv.y;         // q4*y1x
        qd[6] = q4 * yv.z;         // q4*y1y
        qd[7] = q4 * yv.w;         // q4*y1z
    }

    // ---------------- phase C: GEMM1 + silu -> h_s (2 threads/edge) ------
    {
        const int el = t >> 1, half = t & 1;
        const float4* dp4 = (const float4*)(dist_embedding + (size_t)(e0 + el) * 64);
        float z[32];
#pragma unroll
        for (int c = 0; c < 32; ++c) z[c] = 0.f;
#pragma unroll 2
        for (int j4 = 0; j4 < 16; ++j4) {
            float4 d4 = dp4[j4];
            const float dj[4] = {d4.x, d4.y, d4.z, d4.w};
#pragma unroll
            for (int rr = 0; rr < 4; ++rr) {
                const float4* w1r = (const float4*)(W1 + (j4*4 + rr)*64 + half*32);
                const float dv = dj[rr];
#pragma unroll
                for (int q = 0; q < 8; ++q) {
                    float4 a = w1r[q];
                    z[q*4+0] += dv * a.x;
                    z[q*4+1] += dv * a.y;
                    z[q*4+2] += dv * a.z;
                    z[q*4+3] += dv * a.w;
                }
            }
        }
#pragma unroll
        for (int c = 0; c < 32; ++c) {
            const float zz = 0.125f * z[c];
            h_s[(half*32 + c) * EB + el] =
                SILU_NORM * __fdividef(zz, 1.f + __expf(-zz));
        }
    }

    __syncthreads();

    // ---------------- phase D: GEMM2 + TP, cooperative -------------------
    // 32 groups x 8 threads; group g owns edges 4g..4g+3; lane r owns u-chunks.
    const int g = t >> 3, r = t & 7;
    const float* hp = h_s + 4 * g;

#define XQ(e, idx) xq_s[(4*g + (e)) * XQS + (idx)]

    // ---- out0 path: region1 (u=r, u=r+8) + region4 (u=r), coef pre-folded
    float o0p[4][16];
#pragma unroll
    for (int e = 0; e < 4; ++e)
#pragma unroll
        for (int c = 0; c < 16; ++c) o0p[e][c] = 0.f;
    {
        float coef[4];
#pragma unroll
        for (int e = 0; e < 4; ++e) coef[e] = XQ(e,40) * XQ(e,r);          // q0*x0[u]
        acc_chunk<16>(W2 + r*16, hp, coef, o0p);
#pragma unroll
        for (int e = 0; e < 4; ++e) coef[e] = XQ(e,40) * XQ(e,r+8);
        acc_chunk<16>(W2 + (r+8)*16, hp, coef, o0p);
#pragma unroll
        for (int e = 0; e < 4; ++e)                                        // q4*(x1[u].y1)
            coef[e] = XQ(e,45)*XQ(e,16+3*r) + XQ(e,46)*XQ(e,17+3*r) + XQ(e,47)*XQ(e,18+3*r);
        acc_chunk<16>(W2 + 448 + r*16, hp, coef, o0p);
    }
    // butterfly-sum over the 8 u-lanes of the group
#pragma unroll
    for (int m = 1; m <= 4; m <<= 1)
#pragma unroll
        for (int e = 0; e < 4; ++e)
#pragma unroll
            for (int c = 0; c < 16; ++c) o0p[e][c] += __shfl_xor(o0p[e][c], m);
    // one lane per edge flushes o0
#pragma unroll
    for (int e = 0; e < 4; ++e)
        if (r == e) {
            float* op = out + (size_t)src_s[4*g + e] * 40;
#pragma unroll
            for (int c = 0; c < 16; ++c) atomicAdd(op + c, o0p[e][c]);
        }

    // ---- out1 path: region2 (separable, coef=x0[u]) then region3 --------
    float T[4][8];
#pragma unroll
    for (int e = 0; e < 4; ++e)
#pragma unroll
        for (int c = 0; c < 8; ++c) T[e][c] = 0.f;
    {
        float coef[4];
#pragma unroll
        for (int e = 0; e < 4; ++e) coef[e] = XQ(e,r);
        acc_chunk<8>(W2 + 256 + r*8, hp, coef, T);
#pragma unroll
        for (int e = 0; e < 4; ++e) coef[e] = XQ(e,r+8);
        acc_chunk<8>(W2 + 256 + (r+8)*8, hp, coef, T);
    }
    float o1p[4][24];
#pragma unroll
    for (int e = 0; e < 4; ++e) {
        const float c0 = XQ(e,42), c1 = XQ(e,43), c2 = XQ(e,44);
#pragma unroll
        for (int wo = 0; wo < 8; ++wo) {
            o1p[e][wo*3+0] = c0 * T[e][wo];
            o1p[e][wo*3+1] = c1 * T[e][wo];
            o1p[e][wo*3+2] = c2 * T[e][wo];
        }
    }
    // region3: need raw w (per-j scaling), u=r
    {
        float w[4][8];
#pragma unroll
        for (int e = 0; e < 4; ++e)
#pragma unroll
            for (int c = 0; c < 8; ++c) w[e][c] = 0.f;
        const float ones[4] = {1.f, 1.f, 1.f, 1.f};
        acc_chunk<8>(W2 + 384 + r*8, hp, ones, w);
#pragma unroll
        for (int e = 0; e < 4; ++e) {
            const float q3v = XQ(e,41);
            const float c0 = q3v * XQ(e,16+3*r);
            const float c1 = q3v * XQ(e,17+3*r);
            const float c2 = q3v * XQ(e,18+3*r);
#pragma unroll
            for (int wo = 0; wo < 8; ++wo) {
                o1p[e][wo*3+0] += c0 * w[e][wo];
                o1p[e][wo*3+1] += c1 * w[e][wo];
                o1p[e][wo*3+2] += c2 * w[e][wo];
            }
        }
    }
#pragma unroll
    for (int m = 1; m <= 4; m <<= 1)
#pragma unroll
        for (int e = 0; e < 4; ++e)
#pragma unroll
            for (int c = 0; c < 24; ++c) o1p[e][c] += __shfl_xor(o1p[e][c], m);
#pragma unroll
    for (int e = 0; e < 4; ++e)
        if (r == 4 + e) {
            float* op = out + (size_t)src_s[4*g + e] * 40;
#pragma unroll
            for (int c = 0; c < 24; ++c) atomicAdd(op + 16 + c, o1p[e][c]);
        }
#undef XQ
}

extern "C" void kernel_launch(void* const* d_in, const int* in_sizes, int n_in,
                              void* d_out, int out_size, void* d_ws, size_t ws_size,
                              hipStream_t stream)
{
    const float* node_input     = (const float*)d_in[0];
    const int*   edge_src       = (const int*)d_in[1];
    const int*   edge_dst       = (const int*)d_in[2];
    const float* edge_attr      = (const float*)d_in[3];
    const float* dist_embedding = (const float*)d_in[4];
    const float* W1             = (const float*)d_in[5];
    const float* W2             = (const float*)d_in[6];
    float* out = (float*)d_out;

    hipMemsetAsync(out, 0, (size_t)out_size * sizeof(float), stream);
    dim3 grid(N_EDGES / EB);   // 3125, exact
    conv_fused<<<grid, 256, 0, stream>>>(node_input, edge_src, edge_dst,
                                         edge_attr, dist_embedding, W1, W2, out);
}